// Round 1
// baseline (67.809 us; speedup 1.0000x reference)
//
#include <hip/hip_runtime.h>

// Problem constants (from setup_inputs): B=4, P=8192, D=3, cayley is Euclidean
// Cl(3): scalar part of (v * v) == ||v||^2, so the loss is
//   mean_b( sum_i( min_j ||s[b,i] - t[b,j]||^2 ) )  ==  (1/B) * sum over all (b,i) of min d2.
#define BATCH 4
#define NPTS 8192

constexpr int THREADS    = 256;
constexpr int SRC_CHUNK  = 512;                  // source points per block
constexpr int TGT_CHUNK  = 512;                  // target points staged in LDS
constexpr int S_PER_THR  = SRC_CHUNK / THREADS;  // 2 source points per thread

// Order-preserving float<->uint mapping so unsigned atomicMin == float min.
__device__ __forceinline__ unsigned flipf(float x) {
    unsigned u = __float_as_uint(x);
    return (u & 0x80000000u) ? ~u : (u | 0x80000000u);
}
__device__ __forceinline__ float unflipf(unsigned u) {
    u = (u & 0x80000000u) ? (u & 0x7FFFFFFFu) : ~u;
    return __uint_as_float(u);
}

__global__ __launch_bounds__(256) void init_ws_kernel(unsigned* __restrict__ ws) {
    int i = blockIdx.x * blockDim.x + threadIdx.x;
    if (i < BATCH * NPTS) ws[i] = 0xFFFFFFFFu;   // flipped(+inf) upper bound
}

// Each block: SRC_CHUNK source points vs TGT_CHUNK target points (one batch).
// Tracks min over j of m = 0.5*||t||^2 - s.t  (monotone in d2 for fixed s).
__global__ __launch_bounds__(THREADS) void knn_min_kernel(
        const float* __restrict__ src,   // (B, P, 3)
        const float* __restrict__ tgt,   // (B, P, 3)
        unsigned* __restrict__ ws)       // (B*P) flipped min bits
{
    constexpr int NSC = NPTS / SRC_CHUNK;   // 16
    constexpr int NTC = NPTS / TGT_CHUNK;   // 16
    int bid = blockIdx.x;
    int tc  = bid % NTC;
    int sc  = (bid / NTC) % NSC;
    int b   = bid / (NTC * NSC);

    __shared__ float4 tsh[TGT_CHUNK];

    // Stage target tile: (x, y, z, h = 0.5*||t||^2)
    const float* tbase = tgt + ((size_t)b * NPTS + (size_t)tc * TGT_CHUNK) * 3;
    for (int k = threadIdx.x; k < TGT_CHUNK; k += THREADS) {
        float x = tbase[3 * k + 0];
        float y = tbase[3 * k + 1];
        float z = tbase[3 * k + 2];
        float h = 0.5f * (x * x + y * y + z * z);
        tsh[k] = make_float4(x, y, z, h);
    }

    // My source points in registers.
    const float* sbase = src + ((size_t)b * NPTS + (size_t)sc * SRC_CHUNK) * 3;
    float sx[S_PER_THR], sy[S_PER_THR], sz[S_PER_THR], mb[S_PER_THR];
    #pragma unroll
    for (int s = 0; s < S_PER_THR; ++s) {
        int i = threadIdx.x + s * THREADS;
        sx[s] = sbase[3 * i + 0];
        sy[s] = sbase[3 * i + 1];
        sz[s] = sbase[3 * i + 2];
        mb[s] = INFINITY;
    }
    __syncthreads();

    // Inner loop: same-address LDS float4 read broadcasts (conflict-free);
    // 4 VALU ops per pair (3 FMA + 1 min).
    #pragma unroll 8
    for (int j = 0; j < TGT_CHUNK; ++j) {
        float4 t = tsh[j];
        #pragma unroll
        for (int s = 0; s < S_PER_THR; ++s) {
            float m = fmaf(-sx[s], t.x, fmaf(-sy[s], t.y, fmaf(-sz[s], t.z, t.w)));
            mb[s] = fminf(mb[s], m);
        }
    }

    // Merge partial mins across target-chunk blocks (idempotent -> deterministic).
    #pragma unroll
    for (int s = 0; s < S_PER_THR; ++s) {
        int i = sc * SRC_CHUNK + threadIdx.x + s * THREADS;
        atomicMin(&ws[(size_t)b * NPTS + i], flipf(mb[s]));
    }
}

// Single-block deterministic reduction: d2 = ||s||^2 + 2*min_m; out = total / B.
__global__ __launch_bounds__(256) void reduce_kernel(
        const unsigned* __restrict__ ws,
        const float* __restrict__ src,
        float* __restrict__ out)
{
    __shared__ float acc[256];
    float a = 0.0f;
    for (int i = threadIdx.x; i < BATCH * NPTS; i += 256) {
        float m = unflipf(ws[i]);
        float x = src[3 * i + 0];
        float y = src[3 * i + 1];
        float z = src[3 * i + 2];
        float d2 = fmaf(2.0f, m, x * x + y * y + z * z);
        a += d2;
    }
    acc[threadIdx.x] = a;
    __syncthreads();
    for (int off = 128; off > 0; off >>= 1) {
        if (threadIdx.x < off) acc[threadIdx.x] += acc[threadIdx.x + off];
        __syncthreads();
    }
    if (threadIdx.x == 0) out[0] = acc[0] * (1.0f / BATCH);
}

extern "C" void kernel_launch(void* const* d_in, const int* in_sizes, int n_in,
                              void* d_out, int out_size, void* d_ws, size_t ws_size,
                              hipStream_t stream) {
    const float* src = (const float*)d_in[0];   // source_cloud (4, 8192, 3) f32
    const float* tgt = (const float*)d_in[1];   // target_cloud (4, 8192, 3) f32
    // d_in[2] = cayley (8,8,8) — Euclidean; scalar part of v*v == ||v||^2 (see header note)
    float* out = (float*)d_out;
    unsigned* ws = (unsigned*)d_ws;             // B*P * 4 bytes = 128 KiB

    init_ws_kernel<<<(BATCH * NPTS + 255) / 256, 256, 0, stream>>>(ws);

    constexpr int NSC = NPTS / SRC_CHUNK;
    constexpr int NTC = NPTS / TGT_CHUNK;
    knn_min_kernel<<<BATCH * NSC * NTC, THREADS, 0, stream>>>(src, tgt, ws);

    reduce_kernel<<<1, 256, 0, stream>>>(ws, src, out);
}

// Round 2
// 34.584 us; speedup vs baseline: 1.9607x; 1.9607x over previous
//
#include <hip/hip_runtime.h>

// Loss = (1/B) * sum_{b,i} min_j ||s[b,i]-t[b,j]||^2   (Cl(3) scalar part of v*v = ||v||^2).
// We track per-source-point min of h = 0.5*||s||^2 + 0.5*||t||^2 - s.t = 0.5*d2,
// so the final loss = 0.5 * sum(h_min)  (B=4: (1/4)*2 = 0.5).
#define BATCH 4
#define NPTS 8192
#define NTOT (BATCH * NPTS)   // 32768

constexpr int THREADS    = 256;
constexpr int SRC_CHUNK  = 1024;                 // source points per block
constexpr int TGT_CHUNK  = 512;                  // target points staged in LDS
constexpr int S_PER_THR  = SRC_CHUNK / THREADS;  // 4 source points per thread

constexpr int R1_BLOCKS  = 64;                   // stage-1 reduce blocks

// Order-preserving float<->uint mapping so unsigned atomicMin == float min.
__device__ __forceinline__ unsigned flipf(float x) {
    unsigned u = __float_as_uint(x);
    return (u & 0x80000000u) ? ~u : (u | 0x80000000u);
}
__device__ __forceinline__ float unflipf(unsigned u) {
    u = (u & 0x80000000u) ? (u & 0x7FFFFFFFu) : ~u;
    return __uint_as_float(u);
}

__global__ __launch_bounds__(256) void init_ws_kernel(unsigned* __restrict__ ws) {
    int i = blockIdx.x * blockDim.x + threadIdx.x;
    if (i < NTOT) ws[i] = 0xFFFFFFFFu;   // flipped(+inf)
}

// Block = (b, source-chunk, target-chunk). Min over the target tile of
// h = 0.5||s||^2 + 0.5||t||^2 - s.t ; merged across target chunks via atomicMin.
__global__ __launch_bounds__(THREADS) void knn_min_kernel(
        const float* __restrict__ src,   // (B, P, 3)
        const float* __restrict__ tgt,   // (B, P, 3)
        unsigned* __restrict__ ws)       // (NTOT) flipped min bits
{
    constexpr int NSC = NPTS / SRC_CHUNK;   // 8
    constexpr int NTC = NPTS / TGT_CHUNK;   // 16
    int bid = blockIdx.x;
    int tc  = bid % NTC;
    int sc  = (bid / NTC) % NSC;
    int b   = bid / (NTC * NSC);

    __shared__ float4 tsh[TGT_CHUNK];

    // Stage target tile: (x, y, z, 0.5*||t||^2)
    const float* tbase = tgt + ((size_t)b * NPTS + (size_t)tc * TGT_CHUNK) * 3;
    for (int k = threadIdx.x; k < TGT_CHUNK; k += THREADS) {
        float x = tbase[3 * k + 0];
        float y = tbase[3 * k + 1];
        float z = tbase[3 * k + 2];
        tsh[k] = make_float4(x, y, z, 0.5f * (x * x + y * y + z * z));
    }

    // My source points in registers.
    const float* sbase = src + ((size_t)b * NPTS + (size_t)sc * SRC_CHUNK) * 3;
    float sx[S_PER_THR], sy[S_PER_THR], sz[S_PER_THR], mb[S_PER_THR];
    #pragma unroll
    for (int s = 0; s < S_PER_THR; ++s) {
        int i = threadIdx.x + s * THREADS;
        sx[s] = sbase[3 * i + 0];
        sy[s] = sbase[3 * i + 1];
        sz[s] = sbase[3 * i + 2];
        mb[s] = INFINITY;
    }
    __syncthreads();

    // 1 broadcast LDS float4 amortized over 16 VALU ops (4 src pts x (3 fma + 1 min)).
    #pragma unroll 8
    for (int j = 0; j < TGT_CHUNK; ++j) {
        float4 t = tsh[j];
        #pragma unroll
        for (int s = 0; s < S_PER_THR; ++s) {
            float m = fmaf(-sx[s], t.x, fmaf(-sy[s], t.y, fmaf(-sz[s], t.z, t.w)));
            mb[s] = fminf(mb[s], m);
        }
    }

    // Add 0.5*||s||^2 (constant shift per source point; preserves argmin) and merge.
    #pragma unroll
    for (int s = 0; s < S_PER_THR; ++s) {
        int i = sc * SRC_CHUNK + threadIdx.x + s * THREADS;
        float hs = 0.5f * (sx[s] * sx[s] + sy[s] * sy[s] + sz[s] * sz[s]);
        atomicMin(&ws[(size_t)b * NPTS + i], flipf(mb[s] + hs));
    }
}

// Stage 1: 64 blocks x 256 threads, each block sums 512 ws entries -> partials.
__global__ __launch_bounds__(256) void reduce1_kernel(
        const unsigned* __restrict__ ws,
        float* __restrict__ partials)
{
    __shared__ float acc[256];
    int base = blockIdx.x * (NTOT / R1_BLOCKS);   // 512 entries per block
    float a = unflipf(ws[base + threadIdx.x]) + unflipf(ws[base + threadIdx.x + 256]);
    acc[threadIdx.x] = a;
    __syncthreads();
    for (int off = 128; off > 0; off >>= 1) {
        if (threadIdx.x < off) acc[threadIdx.x] += acc[threadIdx.x + off];
        __syncthreads();
    }
    if (threadIdx.x == 0) partials[blockIdx.x] = acc[0];
}

// Stage 2: one wave sums the 64 partials; loss = 0.5 * total.
__global__ __launch_bounds__(64) void reduce2_kernel(
        const float* __restrict__ partials,
        float* __restrict__ out)
{
    float v = partials[threadIdx.x];
    #pragma unroll
    for (int off = 32; off > 0; off >>= 1)
        v += __shfl_down(v, off, 64);
    if (threadIdx.x == 0) out[0] = v * 0.5f;
}

extern "C" void kernel_launch(void* const* d_in, const int* in_sizes, int n_in,
                              void* d_out, int out_size, void* d_ws, size_t ws_size,
                              hipStream_t stream) {
    const float* src = (const float*)d_in[0];   // source_cloud (4, 8192, 3) f32
    const float* tgt = (const float*)d_in[1];   // target_cloud (4, 8192, 3) f32
    // d_in[2] = cayley (8,8,8) — Euclidean; scalar part of v*v == ||v||^2
    float* out = (float*)d_out;
    unsigned* ws  = (unsigned*)d_ws;            // NTOT uints = 128 KiB
    float* partials = (float*)((char*)d_ws + NTOT * sizeof(unsigned));  // 64 floats

    init_ws_kernel<<<(NTOT + 255) / 256, 256, 0, stream>>>(ws);

    constexpr int NSC = NPTS / SRC_CHUNK;
    constexpr int NTC = NPTS / TGT_CHUNK;
    knn_min_kernel<<<BATCH * NSC * NTC, THREADS, 0, stream>>>(src, tgt, ws);

    reduce1_kernel<<<R1_BLOCKS, 256, 0, stream>>>(ws, partials);
    reduce2_kernel<<<1, 64, 0, stream>>>(partials, out);
}

// Round 3
// 33.168 us; speedup vs baseline: 2.0444x; 1.0427x over previous
//
#include <hip/hip_runtime.h>

// Loss = (1/B) * sum_{b,i} min_j ||s[b,i]-t[b,j]||^2  (Cl(3) scalar part of v*v = ||v||^2).
// Track per point the min of h = 0.5||s||^2 + 0.5||t||^2 - s.t = 0.5*d2;
// loss = (1/4) * 2 * sum(h) = 0.5 * sum(h).
#define BATCH 4
#define NPTS 8192
#define NTOT (BATCH * NPTS)   // 32768

constexpr int THREADS   = 256;
constexpr int S_PER_THR = 8;                      // source points per thread (regs)
constexpr int SRC_CHUNK = THREADS * S_PER_THR;    // 2048
constexpr int NSC       = NPTS / SRC_CHUNK;       // 4
constexpr int TGT_CHUNK = 256;                    // targets staged in LDS
constexpr int NTC       = NPTS / TGT_CHUNK;       // 32 slabs
constexpr int R1_BLOCKS = 64;

// Block = (b, src-chunk, tgt-chunk): partial min over its target tile, plain store
// to slab ws[tc][b*NPTS + i]. No atomics, no init pass.
__global__ __launch_bounds__(THREADS) void knn_partial_kernel(
        const float* __restrict__ src,   // (B, P, 3)
        const float* __restrict__ tgt,   // (B, P, 3)
        float* __restrict__ ws)          // (NTC, NTOT) partial h-mins
{
    int bid = blockIdx.x;
    int tc  = bid % NTC;
    int sc  = (bid / NTC) % NSC;
    int b   = bid / (NTC * NSC);

    __shared__ float4 tsh[TGT_CHUNK];

    // Stage target tile: (x, y, z, 0.5*||t||^2). One point per thread.
    {
        const float* tbase = tgt + ((size_t)b * NPTS + (size_t)tc * TGT_CHUNK) * 3;
        int k = threadIdx.x;
        float x = tbase[3 * k + 0];
        float y = tbase[3 * k + 1];
        float z = tbase[3 * k + 2];
        tsh[k] = make_float4(x, y, z, 0.5f * (x * x + y * y + z * z));
    }

    // My 8 source points in registers.
    const float* sbase = src + ((size_t)b * NPTS + (size_t)sc * SRC_CHUNK) * 3;
    float sx[S_PER_THR], sy[S_PER_THR], sz[S_PER_THR], mb[S_PER_THR];
    #pragma unroll
    for (int s = 0; s < S_PER_THR; ++s) {
        int i = threadIdx.x + s * THREADS;
        sx[s] = sbase[3 * i + 0];
        sy[s] = sbase[3 * i + 1];
        sz[s] = sbase[3 * i + 2];
        mb[s] = INFINITY;
    }
    __syncthreads();

    // Per j-pair per thread: 2 ds_read_b128 broadcast + 8*(6 fma + 1 min3-fusable min).
    // One b128 amortized over 8 source points -> VALU-bound, LDS pipe ~75% of VALU.
    #pragma unroll 4
    for (int j = 0; j < TGT_CHUNK; j += 2) {
        float4 t0 = tsh[j];
        float4 t1 = tsh[j + 1];
        #pragma unroll
        for (int s = 0; s < S_PER_THR; ++s) {
            float m0 = fmaf(-sx[s], t0.x, fmaf(-sy[s], t0.y, fmaf(-sz[s], t0.z, t0.w)));
            float m1 = fmaf(-sx[s], t1.x, fmaf(-sy[s], t1.y, fmaf(-sz[s], t1.z, t1.w)));
            mb[s] = fminf(mb[s], fminf(m0, m1));   // -> v_min3_f32
        }
    }

    // h = min_m + 0.5||s||^2 ; plain store into this target-chunk's slab.
    float* wbase = ws + (size_t)tc * NTOT + (size_t)b * NPTS + (size_t)sc * SRC_CHUNK;
    #pragma unroll
    for (int s = 0; s < S_PER_THR; ++s) {
        float hs = 0.5f * (sx[s] * sx[s] + sy[s] * sy[s] + sz[s] * sz[s]);
        wbase[threadIdx.x + s * THREADS] = mb[s] + hs;
    }
}

// Stage 1: 64 blocks; each handles 512 points: final min across the 32 slabs, sum.
__global__ __launch_bounds__(256) void reduce1_kernel(
        const float* __restrict__ ws,
        float* __restrict__ partials)
{
    __shared__ float acc[256];
    int base = blockIdx.x * (NTOT / R1_BLOCKS);   // 512 points per block
    float a = 0.0f;
    #pragma unroll
    for (int p = 0; p < 2; ++p) {
        int i = base + threadIdx.x + p * 256;
        float m = INFINITY;
        #pragma unroll
        for (int sl = 0; sl < NTC; ++sl)
            m = fminf(m, ws[(size_t)sl * NTOT + i]);
        a += m;
    }
    acc[threadIdx.x] = a;
    __syncthreads();
    for (int off = 128; off > 0; off >>= 1) {
        if (threadIdx.x < off) acc[threadIdx.x] += acc[threadIdx.x + off];
        __syncthreads();
    }
    if (threadIdx.x == 0) partials[blockIdx.x] = acc[0];
}

// Stage 2: one wave sums the 64 partials; loss = 0.5 * total.
__global__ __launch_bounds__(64) void reduce2_kernel(
        const float* __restrict__ partials,
        float* __restrict__ out)
{
    float v = partials[threadIdx.x];
    #pragma unroll
    for (int off = 32; off > 0; off >>= 1)
        v += __shfl_down(v, off, 64);
    if (threadIdx.x == 0) out[0] = v * 0.5f;
}

extern "C" void kernel_launch(void* const* d_in, const int* in_sizes, int n_in,
                              void* d_out, int out_size, void* d_ws, size_t ws_size,
                              hipStream_t stream) {
    const float* src = (const float*)d_in[0];   // source_cloud (4, 8192, 3) f32
    const float* tgt = (const float*)d_in[1];   // target_cloud (4, 8192, 3) f32
    // d_in[2] = cayley (8,8,8) — Euclidean; scalar part of v*v == ||v||^2
    float* out = (float*)d_out;
    float* ws  = (float*)d_ws;                  // NTC * NTOT floats = 4 MiB
    float* partials = (float*)((char*)d_ws + (size_t)NTC * NTOT * sizeof(float));

    knn_partial_kernel<<<BATCH * NSC * NTC, THREADS, 0, stream>>>(src, tgt, ws);
    reduce1_kernel<<<R1_BLOCKS, 256, 0, stream>>>(ws, partials);
    reduce2_kernel<<<1, 64, 0, stream>>>(partials, out);
}